// Round 12
// baseline (170.195 us; speedup 1.0000x reference)
//
#include <hip/hip_runtime.h>
#include <math.h>

#define B_  4
#define N_  8192
#define M_  2048
#define O_  64
#define E_  64
#define F_  128
#define K_  7

// RNE f32 -> bf16 (finite inputs; matches numpy/torch round-to-nearest-even)
__device__ __forceinline__ unsigned short f32_to_bf16_rne(float f) {
    unsigned u = __float_as_uint(f);
    u += 0x7FFFu + ((u >> 16) & 1u);
    return (unsigned short)(u >> 16);
}

// ============================================================
// Pre-pass: x (f32) -> x_bf16 (RNE) in d_ws.
// ============================================================
__global__ __launch_bounds__(256) void x_to_bf16_kernel(
    const float* __restrict__ x, unsigned short* __restrict__ xb16)
{
    const size_t i = (size_t)blockIdx.x * 256 + threadIdx.x;   // float4 index
    const float4 v = ((const float4*)x)[i];
    ushort4 o;
    o.x = f32_to_bf16_rne(v.x);
    o.y = f32_to_bf16_rne(v.y);
    o.z = f32_to_bf16_rne(v.z);
    o.w = f32_to_bf16_rne(v.w);
    ((ushort4*)xb16)[i] = o;
}

// ============================================================
// Main fused kernel (R10 structure + XCD swizzle + pipelined gathers).
// 2 independent (b,m) waves per 128-thread block; no barriers.
// ============================================================
__global__ __launch_bounds__(128, 6) void n3agg_kernel(
    const unsigned short* __restrict__ xb16, const float* __restrict__ xe,
    const float* __restrict__ ye, const float* __restrict__ log_temp,
    const int* __restrict__ I, float* __restrict__ out)
{
    __shared__ __align__(16) int   s_I[2][O_];
    __shared__ __align__(16) float s_ye[2][E_];
    __shared__ __align__(16) float s_W[2][O_][8];   // k padded 7->8 for b128 reads

    const int tid  = threadIdx.x;
    const int w    = tid >> 6;
    const int lane = tid & 63;
    // Bijective XCD-chunked swizzle (gridDim.x = 4096, divisible by 8):
    // XCD c hosts blocks blk&7==c -> contiguous sb range -> contiguous bids.
    // 1024 consecutive bids share one batch b -> 2.1MB x-slice fits XCD L2.
    const int nb    = gridDim.x;
    const int chunk = nb >> 3;
    const int blk   = blockIdx.x;
    const int sb    = (blk & 7) * chunk + (blk >> 3);
    const int bid   = sb * 2 + w;            // = b*M_ + m
    const int b     = bid >> 11;             // / 2048

    const int my_idx = I[(size_t)bid * O_ + lane];
    s_I[w][lane]  = my_idx;
    s_ye[w][lane] = ye[(size_t)bid * E_ + lane];

    // ---- Distance, numpy-AVX512 pairwise association (bit-exact, no fma) ----
    const float4* xr4 = (const float4*)(xe + ((size_t)b * N_ + my_idx) * E_);
    const float4* ye4 = (const float4*)(&s_ye[w][0]);
    float S[16];
    #pragma unroll
    for (int q = 0; q < 4; ++q) {
        float4 xa = xr4[q],      ya = ye4[q];
        float4 xb = xr4[q + 4],  yb = ye4[q + 4];
        float4 xc = xr4[q + 8],  yc = ye4[q + 8];
        float4 xd = xr4[q + 12], yd = ye4[q + 12];
        float da, db, dc, dd;

        da = __fsub_rn(xa.x, ya.x); db = __fsub_rn(xb.x, yb.x);
        dc = __fsub_rn(xc.x, yc.x); dd = __fsub_rn(xd.x, yd.x);
        S[4*q+0] = __fadd_rn(__fadd_rn(__fmul_rn(da,da), __fmul_rn(db,db)),
                             __fadd_rn(__fmul_rn(dc,dc), __fmul_rn(dd,dd)));

        da = __fsub_rn(xa.y, ya.y); db = __fsub_rn(xb.y, yb.y);
        dc = __fsub_rn(xc.y, yc.y); dd = __fsub_rn(xd.y, yd.y);
        S[4*q+1] = __fadd_rn(__fadd_rn(__fmul_rn(da,da), __fmul_rn(db,db)),
                             __fadd_rn(__fmul_rn(dc,dc), __fmul_rn(dd,dd)));

        da = __fsub_rn(xa.z, ya.z); db = __fsub_rn(xb.z, yb.z);
        dc = __fsub_rn(xc.z, yc.z); dd = __fsub_rn(xd.z, yd.z);
        S[4*q+2] = __fadd_rn(__fadd_rn(__fmul_rn(da,da), __fmul_rn(db,db)),
                             __fadd_rn(__fmul_rn(dc,dc), __fmul_rn(dd,dd)));

        da = __fsub_rn(xa.w, ya.w); db = __fsub_rn(xb.w, yb.w);
        dc = __fsub_rn(xc.w, yc.w); dd = __fsub_rn(xd.w, yd.w);
        S[4*q+3] = __fadd_rn(__fadd_rn(__fmul_rn(da,da), __fmul_rn(db,db)),
                             __fadd_rn(__fmul_rn(dc,dc), __fmul_rn(dd,dd)));
    }
    float t8[8], t4[4], t2[2], res;
    #pragma unroll
    for (int l = 0; l < 8; ++l) t8[l] = __fadd_rn(S[l], S[l + 8]);
    #pragma unroll
    for (int l = 0; l < 4; ++l) t4[l] = __fadd_rn(t8[l], t8[l + 4]);
    t2[0] = __fadd_rn(t4[0], t4[2]);
    t2[1] = __fadd_rn(t4[1], t4[3]);
    res   = __fadd_rn(t2[0], t2[1]);

    const float temp = expf(log_temp[0]);      // exp(0) = 1.0f exactly
    float logit = __fdiv_rn(-res, temp);

    // ---- K-step relaxed top-k, exact f32 semantics; W kept in registers ----
    float wreg[K_];
    #pragma unroll
    for (int k = 0; k < K_; ++k) {
        float mx = logit;
        #pragma unroll
        for (int d = 1; d < 64; d <<= 1) mx = fmaxf(mx, __shfl_xor(mx, d));
        float sh = __fsub_rn(logit, mx);
        float ex = expf(sh);
        // sum(exp) in AVX512 npyv-pairwise association: xor16, xor32, 8,4,2,1
        float t = __fadd_rn(ex, __shfl_xor(ex, 16));
        t = __fadd_rn(t, __shfl_xor(t, 32));
        t = __fadd_rn(t, __shfl_xor(t, 8));
        t = __fadd_rn(t, __shfl_xor(t, 4));
        t = __fadd_rn(t, __shfl_xor(t, 2));
        t = __fadd_rn(t, __shfl_xor(t, 1));
        const float sm = t;

        float wv = __fsub_rn(sh, logf(sm));
        wreg[k] = expf(wv);

        float lm;
        if (wv < -0.69314718055994530942f) {
            lm = log1pf(-expf(wv));
        } else {
            lm = logf(__fadd_rn(-expm1f(wv), 1e-7f));
        }
        logit = __fadd_rn(logit, lm);
    }
    {
        float* wp = &s_W[w][lane][0];
        *(float4*)wp       = make_float4(wreg[0], wreg[1], wreg[2], wreg[3]);
        *(float2*)(wp + 4) = make_float2(wreg[4], wreg[5]);
        wp[6] = wreg[6];
    }

    // ---- Aggregation: o-parity split; lane owns f-quad 4*(lane&31).
    //      Software-pipelined 4-deep gather (two alternating reg buffers;
    //      uniform control flow, no barrier crossing -> no spill). ----
    const int h  = lane >> 5;                  // 0: even o, 1: odd o
    const int fl = lane & 31;                  // f-quad index
    float acc[4][K_];
    #pragma unroll
    for (int q = 0; q < 4; ++q)
        #pragma unroll
        for (int k = 0; k < K_; ++k) acc[q][k] = 0.f;

    const unsigned short* xb = xb16 + (size_t)b * N_ * F_ + 4 * fl;
    ushort4 bufA[4], bufB[4];
    #pragma unroll
    for (int j = 0; j < 4; ++j)
        bufA[j] = *(const ushort4*)(xb + (size_t)s_I[w][2 * j + h] * F_);

    #pragma unroll
    for (int g = 0; g < 8; ++g) {
        // prefetch group g+1 into the alternate buffer (compile-time select)
        if (g < 7) {
            if ((g & 1) == 0) {
                #pragma unroll
                for (int j = 0; j < 4; ++j)
                    bufB[j] = *(const ushort4*)(xb + (size_t)s_I[w][2*((g+1)*4+j) + h] * F_);
            } else {
                #pragma unroll
                for (int j = 0; j < 4; ++j)
                    bufA[j] = *(const ushort4*)(xb + (size_t)s_I[w][2*((g+1)*4+j) + h] * F_);
            }
        }
        #pragma unroll
        for (int j = 0; j < 4; ++j) {
            const ushort4 xu = ((g & 1) == 0) ? bufA[j] : bufB[j];
            const int o = 2 * (g * 4 + j) + h;
            const float xv0 = __uint_as_float((unsigned)xu.x << 16);
            const float xv1 = __uint_as_float((unsigned)xu.y << 16);
            const float xv2 = __uint_as_float((unsigned)xu.z << 16);
            const float xv3 = __uint_as_float((unsigned)xu.w << 16);
            const float* wrow = &s_W[w][o][0];
            const float4 wa = *(const float4*)(wrow);
            const float4 wb = *(const float4*)(wrow + 4);
            const float wk[K_] = {wa.x, wa.y, wa.z, wa.w, wb.x, wb.y, wb.z};
            #pragma unroll
            for (int k = 0; k < K_; ++k) {
                acc[0][k] = fmaf(wk[k], xv0, acc[0][k]);
                acc[1][k] = fmaf(wk[k], xv1, acc[1][k]);
                acc[2][k] = fmaf(wk[k], xv2, acc[2][k]);
                acc[3][k] = fmaf(wk[k], xv3, acc[3][k]);
            }
        }
    }

    #pragma unroll
    for (int q = 0; q < 4; ++q)
        #pragma unroll
        for (int k = 0; k < K_; ++k)
            acc[q][k] += __shfl_xor(acc[q][k], 32);

    if (lane < 32) {
        // Lane stores 28 contiguous floats; wave covers 3584B contiguous.
        const float* af = &acc[0][0];
        float4* op4 = (float4*)(out + (size_t)bid * F_ * K_ + fl * 28);
        #pragma unroll
        for (int j = 0; j < 7; ++j)
            op4[j] = make_float4(af[4*j], af[4*j+1], af[4*j+2], af[4*j+3]);
    }
}

// ============================================================
// Fallback fused kernel (R6 verbatim, f32 x) if ws too small.
// ============================================================
__global__ __launch_bounds__(128, 6) void n3agg_fused_f32_kernel(
    const float* __restrict__ x, const float* __restrict__ xe,
    const float* __restrict__ ye, const float* __restrict__ log_temp,
    const int* __restrict__ I, float* __restrict__ out)
{
    __shared__ __align__(16) int   s_I[2][O_];
    __shared__ __align__(16) float s_ye[2][E_];
    __shared__ __align__(16) float s_W[2][O_][8];

    const int tid  = threadIdx.x;
    const int w    = tid >> 6;
    const int lane = tid & 63;
    const int bid  = blockIdx.x * 2 + w;
    const int b    = bid >> 11;

    const int my_idx = I[(size_t)bid * O_ + lane];
    s_I[w][lane]  = my_idx;
    s_ye[w][lane] = ye[(size_t)bid * E_ + lane];

    const float4* xr4 = (const float4*)(xe + ((size_t)b * N_ + my_idx) * E_);
    const float4* ye4 = (const float4*)(&s_ye[w][0]);
    float S[16];
    #pragma unroll
    for (int q = 0; q < 4; ++q) {
        float4 xa = xr4[q],      ya = ye4[q];
        float4 xb = xr4[q + 4],  yb = ye4[q + 4];
        float4 xc = xr4[q + 8],  yc = ye4[q + 8];
        float4 xd = xr4[q + 12], yd = ye4[q + 12];
        float da, db, dc, dd;
        da = __fsub_rn(xa.x, ya.x); db = __fsub_rn(xb.x, yb.x);
        dc = __fsub_rn(xc.x, yc.x); dd = __fsub_rn(xd.x, yd.x);
        S[4*q+0] = __fadd_rn(__fadd_rn(__fmul_rn(da,da), __fmul_rn(db,db)),
                             __fadd_rn(__fmul_rn(dc,dc), __fmul_rn(dd,dd)));
        da = __fsub_rn(xa.y, ya.y); db = __fsub_rn(xb.y, yb.y);
        dc = __fsub_rn(xc.y, yc.y); dd = __fsub_rn(xd.y, yd.y);
        S[4*q+1] = __fadd_rn(__fadd_rn(__fmul_rn(da,da), __fmul_rn(db,db)),
                             __fadd_rn(__fmul_rn(dc,dc), __fmul_rn(dd,dd)));
        da = __fsub_rn(xa.z, ya.z); db = __fsub_rn(xb.z, yb.z);
        dc = __fsub_rn(xc.z, yc.z); dd = __fsub_rn(xd.z, yd.z);
        S[4*q+2] = __fadd_rn(__fadd_rn(__fmul_rn(da,da), __fmul_rn(db,db)),
                             __fadd_rn(__fmul_rn(dc,dc), __fmul_rn(dd,dd)));
        da = __fsub_rn(xa.w, ya.w); db = __fsub_rn(xb.w, yb.w);
        dc = __fsub_rn(xc.w, yc.w); dd = __fsub_rn(xd.w, yd.w);
        S[4*q+3] = __fadd_rn(__fadd_rn(__fmul_rn(da,da), __fmul_rn(db,db)),
                             __fadd_rn(__fmul_rn(dc,dc), __fmul_rn(dd,dd)));
    }
    float t8[8], t4[4], t2[2], res;
    #pragma unroll
    for (int l = 0; l < 8; ++l) t8[l] = __fadd_rn(S[l], S[l + 8]);
    #pragma unroll
    for (int l = 0; l < 4; ++l) t4[l] = __fadd_rn(t8[l], t8[l + 4]);
    t2[0] = __fadd_rn(t4[0], t4[2]);
    t2[1] = __fadd_rn(t4[1], t4[3]);
    res   = __fadd_rn(t2[0], t2[1]);

    const float temp = expf(log_temp[0]);
    float logit = __fdiv_rn(-res, temp);

    float wreg[K_];
    #pragma unroll
    for (int k = 0; k < K_; ++k) {
        float mx = logit;
        #pragma unroll
        for (int d = 1; d < 64; d <<= 1) mx = fmaxf(mx, __shfl_xor(mx, d));
        float sh = __fsub_rn(logit, mx);
        float ex = expf(sh);
        float t = __fadd_rn(ex, __shfl_xor(ex, 16));
        t = __fadd_rn(t, __shfl_xor(t, 32));
        t = __fadd_rn(t, __shfl_xor(t, 8));
        t = __fadd_rn(t, __shfl_xor(t, 4));
        t = __fadd_rn(t, __shfl_xor(t, 2));
        t = __fadd_rn(t, __shfl_xor(t, 1));
        const float sm = t;
        float wv = __fsub_rn(sh, logf(sm));
        wreg[k] = expf(wv);
        float lm;
        if (wv < -0.69314718055994530942f) lm = log1pf(-expf(wv));
        else lm = logf(__fadd_rn(-expm1f(wv), 1e-7f));
        logit = __fadd_rn(logit, lm);
    }
    {
        float* wp = &s_W[w][lane][0];
        *(float4*)wp       = make_float4(wreg[0], wreg[1], wreg[2], wreg[3]);
        *(float2*)(wp + 4) = make_float2(wreg[4], wreg[5]);
        wp[6] = wreg[6];
    }

    const int h  = lane >> 5;
    const int fl = lane & 31;
    float acc[4][K_];
    #pragma unroll
    for (int q = 0; q < 4; ++q)
        #pragma unroll
        for (int k = 0; k < K_; ++k) acc[q][k] = 0.f;
    const float* xb = x + (size_t)b * N_ * F_ + 4 * fl;
    #pragma unroll 2
    for (int t = 0; t < 32; ++t) {
        const int o = 2 * t + h;
        const int idx = s_I[w][o];
        const float4 xv = *(const float4*)(xb + (size_t)idx * F_);
        const float* wrow = &s_W[w][o][0];
        const float4 wa = *(const float4*)(wrow);
        const float4 wb = *(const float4*)(wrow + 4);
        const float wk[K_] = {wa.x, wa.y, wa.z, wa.w, wb.x, wb.y, wb.z};
        #pragma unroll
        for (int k = 0; k < K_; ++k) {
            acc[0][k] = fmaf(wk[k], xv.x, acc[0][k]);
            acc[1][k] = fmaf(wk[k], xv.y, acc[1][k]);
            acc[2][k] = fmaf(wk[k], xv.z, acc[2][k]);
            acc[3][k] = fmaf(wk[k], xv.w, acc[3][k]);
        }
    }
    #pragma unroll
    for (int q = 0; q < 4; ++q)
        #pragma unroll
        for (int k = 0; k < K_; ++k)
            acc[q][k] += __shfl_xor(acc[q][k], 32);
    if (lane < 32) {
        const float* af = &acc[0][0];
        float4* op4 = (float4*)(out + (size_t)bid * F_ * K_ + fl * 28);
        #pragma unroll
        for (int j = 0; j < 7; ++j)
            op4[j] = make_float4(af[4*j], af[4*j+1], af[4*j+2], af[4*j+3]);
    }
}

extern "C" void kernel_launch(void* const* d_in, const int* in_sizes, int n_in,
                              void* d_out, int out_size, void* d_ws, size_t ws_size,
                              hipStream_t stream) {
    const float* x        = (const float*)d_in[0];
    const float* xe       = (const float*)d_in[1];
    const float* ye       = (const float*)d_in[2];
    const float* log_temp = (const float*)d_in[3];
    const int*   I        = (const int*)d_in[4];
    float* out = (float*)d_out;

    const size_t need = (size_t)B_ * N_ * F_ * sizeof(unsigned short); // 8.39 MB
    if (ws_size >= need) {
        unsigned short* xb16 = (unsigned short*)d_ws;
        hipLaunchKernelGGL(x_to_bf16_kernel,
                           dim3((B_ * N_ * F_) / 4 / 256), dim3(256), 0, stream,
                           x, xb16);
        hipLaunchKernelGGL(n3agg_kernel, dim3((B_ * M_) / 2), dim3(128),
                           0, stream, xb16, xe, ye, log_temp, I, out);
    } else {
        hipLaunchKernelGGL(n3agg_fused_f32_kernel, dim3((B_ * M_) / 2), dim3(128),
                           0, stream, x, xe, ye, log_temp, I, out);
    }
}

// Round 13
// 67.446 us; speedup vs baseline: 2.5234x; 2.5234x over previous
//
#include <hip/hip_runtime.h>
#include <math.h>

#define B_  4
#define N_  8192
#define M_  2048
#define O_  64
#define E_  64
#define F_  128
#define K_  7

// RNE f32 -> bf16 (finite inputs; matches numpy/torch round-to-nearest-even)
__device__ __forceinline__ unsigned short f32_to_bf16_rne(float f) {
    unsigned u = __float_as_uint(f);
    u += 0x7FFFu + ((u >> 16) & 1u);
    return (unsigned short)(u >> 16);
}

// ============================================================
// Pre-pass: x (f32) -> x_bf16 (RNE) in d_ws.
// ============================================================
__global__ __launch_bounds__(256) void x_to_bf16_kernel(
    const float* __restrict__ x, unsigned short* __restrict__ xb16)
{
    const size_t i = (size_t)blockIdx.x * 256 + threadIdx.x;   // float4 index
    const float4 v = ((const float4*)x)[i];
    ushort4 o;
    o.x = f32_to_bf16_rne(v.x);
    o.y = f32_to_bf16_rne(v.y);
    o.z = f32_to_bf16_rne(v.z);
    o.w = f32_to_bf16_rne(v.w);
    ((ushort4*)xb16)[i] = o;
}

// ============================================================
// Main fused kernel: R10 structure VERBATIM + bijective XCD-chunk swizzle.
// 2 independent (b,m) waves per 128-thread block; no barriers.
// ============================================================
__global__ __launch_bounds__(128, 6) void n3agg_kernel(
    const unsigned short* __restrict__ xb16, const float* __restrict__ xe,
    const float* __restrict__ ye, const float* __restrict__ log_temp,
    const int* __restrict__ I, float* __restrict__ out)
{
    __shared__ __align__(16) int   s_I[2][O_];
    __shared__ __align__(16) float s_ye[2][E_];
    __shared__ __align__(16) float s_W[2][O_][8];   // k padded 7->8 for b128 reads

    const int tid  = threadIdx.x;
    const int w    = tid >> 6;
    const int lane = tid & 63;
    // Bijective XCD-chunk swizzle (gridDim.x = 4096, divisible by 8):
    // XCD c hosts blocks with blk&7==c -> contiguous sb -> contiguous bids.
    // 1024 consecutive bids = half of one batch: x-slice (2.1MB) + xe-slice
    // (2MB) fit the XCD's 4MB L2 -> gathers become L2 hits.
    const int chunk = gridDim.x >> 3;
    const int blk   = blockIdx.x;
    const int sb    = (blk & 7) * chunk + (blk >> 3);
    const int bid   = sb * 2 + w;            // = b*M_ + m
    const int b     = bid >> 11;             // / 2048

    const int my_idx = I[(size_t)bid * O_ + lane];
    s_I[w][lane]  = my_idx;
    s_ye[w][lane] = ye[(size_t)bid * E_ + lane];

    // ---- Distance, numpy-AVX512 pairwise association (bit-exact, no fma) ----
    const float4* xr4 = (const float4*)(xe + ((size_t)b * N_ + my_idx) * E_);
    const float4* ye4 = (const float4*)(&s_ye[w][0]);
    float S[16];
    #pragma unroll
    for (int q = 0; q < 4; ++q) {
        float4 xa = xr4[q],      ya = ye4[q];
        float4 xb = xr4[q + 4],  yb = ye4[q + 4];
        float4 xc = xr4[q + 8],  yc = ye4[q + 8];
        float4 xd = xr4[q + 12], yd = ye4[q + 12];
        float da, db, dc, dd;

        da = __fsub_rn(xa.x, ya.x); db = __fsub_rn(xb.x, yb.x);
        dc = __fsub_rn(xc.x, yc.x); dd = __fsub_rn(xd.x, yd.x);
        S[4*q+0] = __fadd_rn(__fadd_rn(__fmul_rn(da,da), __fmul_rn(db,db)),
                             __fadd_rn(__fmul_rn(dc,dc), __fmul_rn(dd,dd)));

        da = __fsub_rn(xa.y, ya.y); db = __fsub_rn(xb.y, yb.y);
        dc = __fsub_rn(xc.y, yc.y); dd = __fsub_rn(xd.y, yd.y);
        S[4*q+1] = __fadd_rn(__fadd_rn(__fmul_rn(da,da), __fmul_rn(db,db)),
                             __fadd_rn(__fmul_rn(dc,dc), __fmul_rn(dd,dd)));

        da = __fsub_rn(xa.z, ya.z); db = __fsub_rn(xb.z, yb.z);
        dc = __fsub_rn(xc.z, yc.z); dd = __fsub_rn(xd.z, yd.z);
        S[4*q+2] = __fadd_rn(__fadd_rn(__fmul_rn(da,da), __fmul_rn(db,db)),
                             __fadd_rn(__fmul_rn(dc,dc), __fmul_rn(dd,dd)));

        da = __fsub_rn(xa.w, ya.w); db = __fsub_rn(xb.w, yb.w);
        dc = __fsub_rn(xc.w, yc.w); dd = __fsub_rn(xd.w, yd.w);
        S[4*q+3] = __fadd_rn(__fadd_rn(__fmul_rn(da,da), __fmul_rn(db,db)),
                             __fadd_rn(__fmul_rn(dc,dc), __fmul_rn(dd,dd)));
    }
    float t8[8], t4[4], t2[2], res;
    #pragma unroll
    for (int l = 0; l < 8; ++l) t8[l] = __fadd_rn(S[l], S[l + 8]);
    #pragma unroll
    for (int l = 0; l < 4; ++l) t4[l] = __fadd_rn(t8[l], t8[l + 4]);
    t2[0] = __fadd_rn(t4[0], t4[2]);
    t2[1] = __fadd_rn(t4[1], t4[3]);
    res   = __fadd_rn(t2[0], t2[1]);

    const float temp = expf(log_temp[0]);      // exp(0) = 1.0f exactly
    float logit = __fdiv_rn(-res, temp);

    // ---- K-step relaxed top-k, exact f32 semantics; W kept in registers ----
    float wreg[K_];
    #pragma unroll
    for (int k = 0; k < K_; ++k) {
        float mx = logit;
        #pragma unroll
        for (int d = 1; d < 64; d <<= 1) mx = fmaxf(mx, __shfl_xor(mx, d));
        float sh = __fsub_rn(logit, mx);
        float ex = expf(sh);
        // sum(exp) in AVX512 npyv-pairwise association: xor16, xor32, 8,4,2,1
        float t = __fadd_rn(ex, __shfl_xor(ex, 16));
        t = __fadd_rn(t, __shfl_xor(t, 32));
        t = __fadd_rn(t, __shfl_xor(t, 8));
        t = __fadd_rn(t, __shfl_xor(t, 4));
        t = __fadd_rn(t, __shfl_xor(t, 2));
        t = __fadd_rn(t, __shfl_xor(t, 1));
        const float sm = t;

        float wv = __fsub_rn(sh, logf(sm));
        wreg[k] = expf(wv);

        float lm;
        if (wv < -0.69314718055994530942f) {
            lm = log1pf(-expf(wv));
        } else {
            lm = logf(__fadd_rn(-expm1f(wv), 1e-7f));
        }
        logit = __fadd_rn(logit, lm);
    }
    {
        float* wp = &s_W[w][lane][0];
        *(float4*)wp       = make_float4(wreg[0], wreg[1], wreg[2], wreg[3]);
        *(float2*)(wp + 4) = make_float2(wreg[4], wreg[5]);
        wp[6] = wreg[6];
    }

    // ---- Aggregation: o-parity split; lane owns f-quad 4*(lane&31) ----
    // Gathers 256B bf16 rows; widen via (u<<16) bit-shift (exact).
    const int h  = lane >> 5;                  // 0: even o, 1: odd o
    const int fl = lane & 31;                  // f-quad index
    float acc[4][K_];
    #pragma unroll
    for (int q = 0; q < 4; ++q)
        #pragma unroll
        for (int k = 0; k < K_; ++k) acc[q][k] = 0.f;

    const unsigned short* xb = xb16 + (size_t)b * N_ * F_ + 4 * fl;
    #pragma unroll 2
    for (int t = 0; t < 32; ++t) {
        const int o = 2 * t + h;
        const int idx = s_I[w][o];
        const ushort4 xu = *(const ushort4*)(xb + (size_t)idx * F_);
        const float xv0 = __uint_as_float((unsigned)xu.x << 16);
        const float xv1 = __uint_as_float((unsigned)xu.y << 16);
        const float xv2 = __uint_as_float((unsigned)xu.z << 16);
        const float xv3 = __uint_as_float((unsigned)xu.w << 16);
        const float* wrow = &s_W[w][o][0];
        const float4 wa = *(const float4*)(wrow);
        const float4 wb = *(const float4*)(wrow + 4);
        const float wk[K_] = {wa.x, wa.y, wa.z, wa.w, wb.x, wb.y, wb.z};
        #pragma unroll
        for (int k = 0; k < K_; ++k) {
            acc[0][k] = fmaf(wk[k], xv0, acc[0][k]);
            acc[1][k] = fmaf(wk[k], xv1, acc[1][k]);
            acc[2][k] = fmaf(wk[k], xv2, acc[2][k]);
            acc[3][k] = fmaf(wk[k], xv3, acc[3][k]);
        }
    }
    #pragma unroll
    for (int q = 0; q < 4; ++q)
        #pragma unroll
        for (int k = 0; k < K_; ++k)
            acc[q][k] += __shfl_xor(acc[q][k], 32);

    if (lane < 32) {
        const float* af = &acc[0][0];
        float4* op4 = (float4*)(out + (size_t)bid * F_ * K_ + fl * 28);
        #pragma unroll
        for (int j = 0; j < 7; ++j)
            op4[j] = make_float4(af[4*j], af[4*j+1], af[4*j+2], af[4*j+3]);
    }
}

// ============================================================
// Fallback fused kernel (R6 verbatim, f32 x) if ws too small.
// ============================================================
__global__ __launch_bounds__(128, 6) void n3agg_fused_f32_kernel(
    const float* __restrict__ x, const float* __restrict__ xe,
    const float* __restrict__ ye, const float* __restrict__ log_temp,
    const int* __restrict__ I, float* __restrict__ out)
{
    __shared__ __align__(16) int   s_I[2][O_];
    __shared__ __align__(16) float s_ye[2][E_];
    __shared__ __align__(16) float s_W[2][O_][8];

    const int tid  = threadIdx.x;
    const int w    = tid >> 6;
    const int lane = tid & 63;
    const int bid  = blockIdx.x * 2 + w;
    const int b    = bid >> 11;

    const int my_idx = I[(size_t)bid * O_ + lane];
    s_I[w][lane]  = my_idx;
    s_ye[w][lane] = ye[(size_t)bid * E_ + lane];

    const float4* xr4 = (const float4*)(xe + ((size_t)b * N_ + my_idx) * E_);
    const float4* ye4 = (const float4*)(&s_ye[w][0]);
    float S[16];
    #pragma unroll
    for (int q = 0; q < 4; ++q) {
        float4 xa = xr4[q],      ya = ye4[q];
        float4 xb = xr4[q + 4],  yb = ye4[q + 4];
        float4 xc = xr4[q + 8],  yc = ye4[q + 8];
        float4 xd = xr4[q + 12], yd = ye4[q + 12];
        float da, db, dc, dd;
        da = __fsub_rn(xa.x, ya.x); db = __fsub_rn(xb.x, yb.x);
        dc = __fsub_rn(xc.x, yc.x); dd = __fsub_rn(xd.x, yd.x);
        S[4*q+0] = __fadd_rn(__fadd_rn(__fmul_rn(da,da), __fmul_rn(db,db)),
                             __fadd_rn(__fmul_rn(dc,dc), __fmul_rn(dd,dd)));
        da = __fsub_rn(xa.y, ya.y); db = __fsub_rn(xb.y, yb.y);
        dc = __fsub_rn(xc.y, yc.y); dd = __fsub_rn(xd.y, yd.y);
        S[4*q+1] = __fadd_rn(__fadd_rn(__fmul_rn(da,da), __fmul_rn(db,db)),
                             __fadd_rn(__fmul_rn(dc,dc), __fmul_rn(dd,dd)));
        da = __fsub_rn(xa.z, ya.z); db = __fsub_rn(xb.z, yb.z);
        dc = __fsub_rn(xc.z, yc.z); dd = __fsub_rn(xd.z, yd.z);
        S[4*q+2] = __fadd_rn(__fadd_rn(__fmul_rn(da,da), __fmul_rn(db,db)),
                             __fadd_rn(__fmul_rn(dc,dc), __fmul_rn(dd,dd)));
        da = __fsub_rn(xa.w, ya.w); db = __fsub_rn(xb.w, yb.w);
        dc = __fsub_rn(xc.w, yc.w); dd = __fsub_rn(xd.w, yd.w);
        S[4*q+3] = __fadd_rn(__fadd_rn(__fmul_rn(da,da), __fmul_rn(db,db)),
                             __fadd_rn(__fmul_rn(dc,dc), __fmul_rn(dd,dd)));
    }
    float t8[8], t4[4], t2[2], res;
    #pragma unroll
    for (int l = 0; l < 8; ++l) t8[l] = __fadd_rn(S[l], S[l + 8]);
    #pragma unroll
    for (int l = 0; l < 4; ++l) t4[l] = __fadd_rn(t8[l], t8[l + 4]);
    t2[0] = __fadd_rn(t4[0], t4[2]);
    t2[1] = __fadd_rn(t4[1], t4[3]);
    res   = __fadd_rn(t2[0], t2[1]);

    const float temp = expf(log_temp[0]);
    float logit = __fdiv_rn(-res, temp);

    float wreg[K_];
    #pragma unroll
    for (int k = 0; k < K_; ++k) {
        float mx = logit;
        #pragma unroll
        for (int d = 1; d < 64; d <<= 1) mx = fmaxf(mx, __shfl_xor(mx, d));
        float sh = __fsub_rn(logit, mx);
        float ex = expf(sh);
        float t = __fadd_rn(ex, __shfl_xor(ex, 16));
        t = __fadd_rn(t, __shfl_xor(t, 32));
        t = __fadd_rn(t, __shfl_xor(t, 8));
        t = __fadd_rn(t, __shfl_xor(t, 4));
        t = __fadd_rn(t, __shfl_xor(t, 2));
        t = __fadd_rn(t, __shfl_xor(t, 1));
        const float sm = t;
        float wv = __fsub_rn(sh, logf(sm));
        wreg[k] = expf(wv);
        float lm;
        if (wv < -0.69314718055994530942f) lm = log1pf(-expf(wv));
        else lm = logf(__fadd_rn(-expm1f(wv), 1e-7f));
        logit = __fadd_rn(logit, lm);
    }
    {
        float* wp = &s_W[w][lane][0];
        *(float4*)wp       = make_float4(wreg[0], wreg[1], wreg[2], wreg[3]);
        *(float2*)(wp + 4) = make_float2(wreg[4], wreg[5]);
        wp[6] = wreg[6];
    }

    const int h  = lane >> 5;
    const int fl = lane & 31;
    float acc[4][K_];
    #pragma unroll
    for (int q = 0; q < 4; ++q)
        #pragma unroll
        for (int k = 0; k < K_; ++k) acc[q][k] = 0.f;
    const float* xb = x + (size_t)b * N_ * F_ + 4 * fl;
    #pragma unroll 2
    for (int t = 0; t < 32; ++t) {
        const int o = 2 * t + h;
        const int idx = s_I[w][o];
        const float4 xv = *(const float4*)(xb + (size_t)idx * F_);
        const float* wrow = &s_W[w][o][0];
        const float4 wa = *(const float4*)(wrow);
        const float4 wb = *(const float4*)(wrow + 4);
        const float wk[K_] = {wa.x, wa.y, wa.z, wa.w, wb.x, wb.y, wb.z};
        #pragma unroll
        for (int k = 0; k < K_; ++k) {
            acc[0][k] = fmaf(wk[k], xv.x, acc[0][k]);
            acc[1][k] = fmaf(wk[k], xv.y, acc[1][k]);
            acc[2][k] = fmaf(wk[k], xv.z, acc[2][k]);
            acc[3][k] = fmaf(wk[k], xv.w, acc[3][k]);
        }
    }
    #pragma unroll
    for (int q = 0; q < 4; ++q)
        #pragma unroll
        for (int k = 0; k < K_; ++k)
            acc[q][k] += __shfl_xor(acc[q][k], 32);
    if (lane < 32) {
        const float* af = &acc[0][0];
        float4* op4 = (float4*)(out + (size_t)bid * F_ * K_ + fl * 28);
        #pragma unroll
        for (int j = 0; j < 7; ++j)
            op4[j] = make_float4(af[4*j], af[4*j+1], af[4*j+2], af[4*j+3]);
    }
}

extern "C" void kernel_launch(void* const* d_in, const int* in_sizes, int n_in,
                              void* d_out, int out_size, void* d_ws, size_t ws_size,
                              hipStream_t stream) {
    const float* x        = (const float*)d_in[0];
    const float* xe       = (const float*)d_in[1];
    const float* ye       = (const float*)d_in[2];
    const float* log_temp = (const float*)d_in[3];
    const int*   I        = (const int*)d_in[4];
    float* out = (float*)d_out;

    const size_t need = (size_t)B_ * N_ * F_ * sizeof(unsigned short); // 8.39 MB
    if (ws_size >= need) {
        unsigned short* xb16 = (unsigned short*)d_ws;
        hipLaunchKernelGGL(x_to_bf16_kernel,
                           dim3((B_ * N_ * F_) / 4 / 256), dim3(256), 0, stream,
                           x, xb16);
        hipLaunchKernelGGL(n3agg_kernel, dim3((B_ * M_) / 2), dim3(128),
                           0, stream, xb16, xe, ye, log_temp, I, out);
    } else {
        hipLaunchKernelGGL(n3agg_fused_f32_kernel, dim3((B_ * M_) / 2), dim3(128),
                           0, stream, x, xe, ye, log_temp, I, out);
    }
}